// Round 1
// baseline (400.386 us; speedup 1.0000x reference)
//
#include <hip/hip_runtime.h>
#include <math.h>

#define B 2
#define C 32
#define H 128
#define W 416
#define D 48
#define HW (H*W)
#define CHW (C*HW)
#define EPSN 1e-3f
#define ISCALE 0.05892556509887896f   // 1/sqrt(C*9)

__device__ __forceinline__ float clip10(float x) {
    return fminf(fmaxf(x, -10.0f), 10.0f);
}

// ---------------------------------------------------------------------------
// k_sq: per-pixel sum over channels of squares for xl/xr; inverse norm for xm.
// one thread per (b,h,w)
__global__ __launch_bounds__(256) void k_sq(const float* __restrict__ xl,
                                            const float* __restrict__ xr,
                                            const float* __restrict__ xm,
                                            float* __restrict__ sql,
                                            float* __restrict__ sqr,
                                            float* __restrict__ inm) {
    int idx = blockIdx.x * 256 + threadIdx.x;   // [0, B*HW)
    if (idx >= B * HW) return;
    int b = idx / HW, hw = idx - b * HW;
    const float* pl = xl + (size_t)b * CHW + hw;
    const float* pr = xr + (size_t)b * CHW + hw;
    const float* pm = xm + (size_t)b * CHW + hw;
    float al = 0.f, ar = 0.f, am = 0.f;
#pragma unroll
    for (int c = 0; c < C; ++c) {
        float vl = pl[c * HW], vr = pr[c * HW], vm = pm[c * HW];
        al += vl * vl; ar += vr * vr; am += vm * vm;
    }
    sql[idx] = al;
    sqr[idx] = ar;
    inm[idx] = 1.0f / fmaxf(sqrtf(am), EPSN);
}

// ---------------------------------------------------------------------------
// k_norm: 3x3 zero-padded box of sql/sqr -> inverse patch norms inl/inr.
__global__ __launch_bounds__(256) void k_norm(const float* __restrict__ sql,
                                              const float* __restrict__ sqr,
                                              float* __restrict__ inl,
                                              float* __restrict__ inr) {
    int idx = blockIdx.x * 256 + threadIdx.x;
    if (idx >= B * HW) return;
    int b = idx / HW, hw = idx - b * HW;
    int h = hw / W, w = hw - h * W;
    float sl = 0.f, sr = 0.f;
#pragma unroll
    for (int di = -1; di <= 1; ++di) {
        int hh = h + di;
        if (hh < 0 || hh >= H) continue;
#pragma unroll
        for (int dj = -1; dj <= 1; ++dj) {
            int ww = w + dj;
            if (ww < 0 || ww >= W) continue;
            int p = b * HW + hh * W + ww;
            sl += sql[p];
            sr += sqr[p];
        }
    }
    inl[idx] = 1.0f / fmaxf(sqrtf(sl), EPSN);
    inr[idx] = 1.0f / fmaxf(sqrtf(sr), EPSN);
}

// ---------------------------------------------------------------------------
// k_box: per-channel 3x3 zero-padded box sums of xl and xr.
// one thread per element of [B,C,H,W]
__global__ __launch_bounds__(256) void k_box(const float* __restrict__ xl,
                                             const float* __restrict__ xr,
                                             float* __restrict__ boxl,
                                             float* __restrict__ boxr) {
    int idx = blockIdx.x * 256 + threadIdx.x;   // [0, B*C*H*W)
    int w = idx % W;
    int h = (idx / W) % H;
    int rest = idx / HW;                        // b*C + c
    size_t base = (size_t)rest * HW;
    float al = 0.f, ar = 0.f;
#pragma unroll
    for (int di = -1; di <= 1; ++di) {
        int hh = h + di;
        if (hh < 0 || hh >= H) continue;
#pragma unroll
        for (int dj = -1; dj <= 1; ++dj) {
            int ww = w + dj;
            if (ww < 0 || ww >= W) continue;
            al += xl[base + hh * W + ww];
            ar += xr[base + hh * W + ww];
        }
    }
    boxl[idx] = al;
    boxr[idx] = ar;
}

// ---------------------------------------------------------------------------
// k_eh: E_{2d}[b,h,v] = sum_c xl[b,c,h,v+2d]*xr[b,c,h,v]  (0 when v+2d>=W),
// then horizontal 3-tap sum -> EH[b,d,h,v]. xr column held in registers
// across the 12 disparities this block handles.
#define DCH 12
__global__ __launch_bounds__(256) void k_eh(const float* __restrict__ xl,
                                            const float* __restrict__ xr,
                                            float* __restrict__ EH) {
    __shared__ float lds[258];
    int tid = threadIdx.x;
    int chunk = blockIdx.x;            // 0,1 -> v base 0 / 256
    int h = blockIdx.y;
    int z = blockIdx.z;                // b*4 + dchunk
    int b = z >> 2;
    int dc = z & 3;
    int v = chunk * 256 + tid;
    const float* bl = xl + (size_t)b * CHW + h * W;
    const float* br = xr + (size_t)b * CHW + h * W;

    bool vin = v < W;
    float xrv[C];
#pragma unroll
    for (int c = 0; c < C; ++c) xrv[c] = vin ? br[c * HW + v] : 0.0f;

    for (int i = 0; i < DCH; ++i) {
        int d = dc * DCH + i;
        int s = 2 * d;
        float e = 0.0f;
        if (v + s < W) {
#pragma unroll
            for (int c = 0; c < C; ++c) e += xrv[c] * bl[c * HW + v + s];
        }
        lds[tid + 1] = e;
        if (tid == 0) {
            int vn = chunk * 256 - 1;
            float en = 0.0f;
            if (vn >= 0 && vn + s < W) {
#pragma unroll
                for (int c = 0; c < C; ++c) en += br[c * HW + vn] * bl[c * HW + vn + s];
            }
            lds[0] = en;
        }
        if (tid == 255) {
            int vn = chunk * 256 + 256;
            float en = 0.0f;
            if (vn + s < W) {
#pragma unroll
                for (int c = 0; c < C; ++c) en += br[c * HW + vn] * bl[c * HW + vn + s];
            }
            lds[257] = en;
        }
        __syncthreads();
        if (vin) {
            float eh = lds[tid] + lds[tid + 1] + lds[tid + 2];
            EH[(((size_t)b * D + d) * H + h) * W + v] = eh;
        }
        __syncthreads();
    }
}

// ---------------------------------------------------------------------------
// k_lr: sL and sR. One thread per (b,h,w); fl (normalized xm column) held in
// 32 registers across the 12 disparities of this block.
__global__ __launch_bounds__(448) void k_lr(const float* __restrict__ xm,
                                            const float* __restrict__ boxl,
                                            const float* __restrict__ boxr,
                                            const float* __restrict__ inl,
                                            const float* __restrict__ inr,
                                            const float* __restrict__ inm,
                                            float* __restrict__ out) {
    int w = threadIdx.x;               // 0..447
    int dc = blockIdx.x;               // 0..3
    int h = blockIdx.y;
    int b = blockIdx.z;
    if (w >= W) return;                // no barriers below

    int bhw = b * HW + h * W;
    const float* pm = xm + (size_t)b * CHW + h * W;
    const float* pbl = boxl + (size_t)b * CHW + h * W;
    const float* pbr = boxr + (size_t)b * CHW + h * W;

    float im = inm[bhw + w];
    float fl[C];
#pragma unroll
    for (int c = 0; c < C; ++c) fl[c] = pm[c * HW + w] * im;

    for (int i = 0; i < DCH; ++i) {
        int d = dc * DCH + i;
        float oL = 0.0f, oR = 0.0f;
        if (w + d < W) {
            float a = 0.0f;
#pragma unroll
            for (int c = 0; c < C; ++c) a += fl[c] * pbl[c * HW + w + d];
            oL = clip10(a * inl[bhw + w + d] * ISCALE);
        }
        if (w - d >= 0) {
            float a = 0.0f;
#pragma unroll
            for (int c = 0; c < C; ++c) a += fl[c] * pbr[c * HW + w - d];
            oR = clip10(a * inr[bhw + w - d] * ISCALE);
        }
        out[(((size_t)b * 3 + 0) * D + d) * HW + h * W + w] = oL;
        out[(((size_t)b * 3 + 1) * D + d) * HW + h * W + w] = oR;
    }
}

// ---------------------------------------------------------------------------
// k_lr2: sLR = vertical 3-tap of EH at column w-d, times inverse norms.
__global__ __launch_bounds__(256) void k_lr2(const float* __restrict__ EH,
                                             const float* __restrict__ inl,
                                             const float* __restrict__ inr,
                                             float* __restrict__ out) {
    int tid = threadIdx.x;
    int chunk = blockIdx.x;            // 0,1
    int h = blockIdx.y;
    int z = blockIdx.z;                // b*4 + dchunk
    int b = z >> 2;
    int dc = z & 3;
    int w = chunk * 256 + tid;
    if (w >= W) return;
    int bhw = b * HW + h * W;

    for (int i = 0; i < DCH; ++i) {
        int d = dc * DCH + i;
        float o = 0.0f;
        if (w >= d && w + d < W) {
            int vc = w - d;
            const float* pe = EH + (((size_t)b * D + d) * H) * W + vc;
            float e = pe[h * W];
            if (h > 0) e += pe[(h - 1) * W];
            if (h < H - 1) e += pe[(h + 1) * W];
            o = clip10(e * inl[bhw + w + d] * inr[bhw + vc] * ISCALE);
        }
        out[(((size_t)b * 3 + 2) * D + d) * HW + h * W + w] = o;
    }
}

// ---------------------------------------------------------------------------
extern "C" void kernel_launch(void* const* d_in, const int* in_sizes, int n_in,
                              void* d_out, int out_size, void* d_ws, size_t ws_size,
                              hipStream_t stream) {
    const float* xl = (const float*)d_in[0];
    const float* xm = (const float*)d_in[1];
    const float* xr = (const float*)d_in[2];
    float* out = (float*)d_out;

    float* ws = (float*)d_ws;
    float* boxl = ws;                              // B*C*H*W
    float* boxr = boxl + (size_t)B * CHW;          // B*C*H*W
    float* inl  = boxr + (size_t)B * CHW;          // B*HW
    float* inr  = inl + B * HW;                    // B*HW
    float* inm  = inr + B * HW;                    // B*HW
    float* sql  = inm + B * HW;                    // B*HW
    float* sqr  = sql + B * HW;                    // B*HW
    float* EH   = sqr + B * HW;                    // B*D*H*W

    k_sq<<<dim3((B * HW + 255) / 256), dim3(256), 0, stream>>>(xl, xr, xm, sql, sqr, inm);
    k_norm<<<dim3((B * HW + 255) / 256), dim3(256), 0, stream>>>(sql, sqr, inl, inr);
    k_box<<<dim3((B * CHW + 255) / 256), dim3(256), 0, stream>>>(xl, xr, boxl, boxr);
    k_eh<<<dim3(2, H, B * 4), dim3(256), 0, stream>>>(xl, xr, EH);
    k_lr<<<dim3(4, H, B), dim3(448), 0, stream>>>(xm, boxl, boxr, inl, inr, inm, out);
    k_lr2<<<dim3(2, H, B * 4), dim3(256), 0, stream>>>(EH, inl, inr, out);
}

// Round 2
// 259.669 us; speedup vs baseline: 1.5419x; 1.5419x over previous
//
#include <hip/hip_runtime.h>
#include <math.h>

#define B 2
#define C 32
#define H 128
#define W 416
#define D 48
#define HW (H*W)
#define CHW (C*HW)
#define EPSN 1e-3f
#define ISCALE 0.05892556509887896f   // 1/sqrt(C*9)
#define LSTR 36                        // LDS column stride (floats): 16B-aligned, bank-uniform

__device__ __forceinline__ float clip10(float x) {
    return fminf(fmaxf(x, -10.0f), 10.0f);
}

// ---------------------------------------------------------------------------
// k_sq: per-pixel sum over channels of squares for xl/xr; inverse norm for xm.
__global__ __launch_bounds__(256) void k_sq(const float* __restrict__ xl,
                                            const float* __restrict__ xr,
                                            const float* __restrict__ xm,
                                            float* __restrict__ sql,
                                            float* __restrict__ sqr,
                                            float* __restrict__ inm) {
    int idx = blockIdx.x * 256 + threadIdx.x;   // [0, B*HW)
    if (idx >= B * HW) return;
    int b = idx / HW, hw = idx - b * HW;
    const float* pl = xl + (size_t)b * CHW + hw;
    const float* pr = xr + (size_t)b * CHW + hw;
    const float* pm = xm + (size_t)b * CHW + hw;
    float al = 0.f, ar = 0.f, am = 0.f;
#pragma unroll
    for (int c = 0; c < C; ++c) {
        float vl = pl[c * HW], vr = pr[c * HW], vm = pm[c * HW];
        al += vl * vl; ar += vr * vr; am += vm * vm;
    }
    sql[idx] = al;
    sqr[idx] = ar;
    inm[idx] = 1.0f / fmaxf(sqrtf(am), EPSN);
}

// ---------------------------------------------------------------------------
// k_norm: 3x3 zero-padded box of sql/sqr -> inverse patch norms inl/inr.
__global__ __launch_bounds__(256) void k_norm(const float* __restrict__ sql,
                                              const float* __restrict__ sqr,
                                              float* __restrict__ inl,
                                              float* __restrict__ inr) {
    int idx = blockIdx.x * 256 + threadIdx.x;
    if (idx >= B * HW) return;
    int b = idx / HW, hw = idx - b * HW;
    int h = hw / W, w = hw - h * W;
    float sl = 0.f, sr = 0.f;
#pragma unroll
    for (int di = -1; di <= 1; ++di) {
        int hh = h + di;
        if (hh < 0 || hh >= H) continue;
#pragma unroll
        for (int dj = -1; dj <= 1; ++dj) {
            int ww = w + dj;
            if (ww < 0 || ww >= W) continue;
            int p = b * HW + hh * W + ww;
            sl += sql[p];
            sr += sqr[p];
        }
    }
    inl[idx] = 1.0f / fmaxf(sqrtf(sl), EPSN);
    inr[idx] = 1.0f / fmaxf(sqrtf(sr), EPSN);
}

// ---------------------------------------------------------------------------
// k_box: per-channel 3x3 zero-padded box sums of xl and xr.
__global__ __launch_bounds__(256) void k_box(const float* __restrict__ xl,
                                             const float* __restrict__ xr,
                                             float* __restrict__ boxl,
                                             float* __restrict__ boxr) {
    int idx = blockIdx.x * 256 + threadIdx.x;   // [0, B*C*H*W)
    int w = idx % W;
    int h = (idx / W) % H;
    int rest = idx / HW;                        // b*C + c
    size_t base = (size_t)rest * HW;
    float al = 0.f, ar = 0.f;
#pragma unroll
    for (int di = -1; di <= 1; ++di) {
        int hh = h + di;
        if (hh < 0 || hh >= H) continue;
#pragma unroll
        for (int dj = -1; dj <= 1; ++dj) {
            int ww = w + dj;
            if (ww < 0 || ww >= W) continue;
            al += xl[base + hh * W + ww];
            ar += xr[base + hh * W + ww];
        }
    }
    boxl[idx] = al;
    boxr[idx] = ar;
}

// ---------------------------------------------------------------------------
// helper: stage one [C][W] global row into LDS transposed [w][c] with stride LSTR
__device__ __forceinline__ void stage_row(const float* __restrict__ gsrc,
                                          float* __restrict__ lds, int tid, int nthreads) {
    // 416*32/4 = 3328 float4 loads
    for (int j = tid; j < (W / 4) * C; j += nthreads) {
        int c = j / (W / 4);
        int w4 = (j - c * (W / 4)) * 4;
        float4 v = *(const float4*)(gsrc + (size_t)c * HW + w4);
        lds[(w4 + 0) * LSTR + c] = v.x;
        lds[(w4 + 1) * LSTR + c] = v.y;
        lds[(w4 + 2) * LSTR + c] = v.z;
        lds[(w4 + 3) * LSTR + c] = v.w;
    }
}

__device__ __forceinline__ float dot32(const float* __restrict__ fl,
                                       const float* __restrict__ col) {
    const float4* c4 = (const float4*)col;   // col is 16B-aligned (LSTR*4 = 144 = 9*16)
    float a = 0.0f;
#pragma unroll
    for (int q = 0; q < 8; ++q) {
        float4 v = c4[q];
        a += fl[4 * q + 0] * v.x + fl[4 * q + 1] * v.y
           + fl[4 * q + 2] * v.z + fl[4 * q + 3] * v.w;
    }
    return a;
}

// ---------------------------------------------------------------------------
// k_lr: sL and sR for all 48 d. One block per (b,h). Two phases sharing one
// 60KB LDS buffer: stage boxl -> compute sL; stage boxr -> compute sR.
__global__ __launch_bounds__(448) void k_lr(const float* __restrict__ xm,
                                            const float* __restrict__ boxl,
                                            const float* __restrict__ boxr,
                                            const float* __restrict__ inl,
                                            const float* __restrict__ inr,
                                            const float* __restrict__ inm,
                                            float* __restrict__ out) {
    __shared__ float sB[W * LSTR];    // 59904 B
    __shared__ float sIn[W];
    int tid = threadIdx.x;
    int h = blockIdx.x;
    int b = blockIdx.y;
    int w = tid;
    bool act = w < W;
    int bhw = b * HW + h * W;
    const float* pm = xm + (size_t)b * CHW + h * W;

    float fl[C];
    float im = act ? inm[bhw + w] : 0.0f;
#pragma unroll
    for (int c = 0; c < C; ++c) fl[c] = act ? pm[c * HW + w] * im : 0.0f;

    // ---- phase L ----
    stage_row(boxl + (size_t)b * CHW + h * W, sB, tid, 448);
    for (int j = tid; j < W; j += 448) sIn[j] = inl[bhw + j];
    __syncthreads();
    if (act) {
        float* o = out + ((size_t)b * 3 + 0) * D * HW + h * W + w;
        for (int d = 0; d < D; ++d) {
            float oL = 0.0f;
            int v = w + d;
            if (v < W) {
                float a = dot32(fl, sB + v * LSTR);
                oL = clip10(a * sIn[v] * ISCALE);
            }
            o[(size_t)d * HW] = oL;
        }
    }
    __syncthreads();

    // ---- phase R ----
    stage_row(boxr + (size_t)b * CHW + h * W, sB, tid, 448);
    for (int j = tid; j < W; j += 448) sIn[j] = inr[bhw + j];
    __syncthreads();
    if (act) {
        float* o = out + ((size_t)b * 3 + 1) * D * HW + h * W + w;
        for (int d = 0; d < D; ++d) {
            float oR = 0.0f;
            int v = w - d;
            if (v >= 0) {
                float a = dot32(fl, sB + v * LSTR);
                oR = clip10(a * sIn[v] * ISCALE);
            }
            o[(size_t)d * HW] = oR;
        }
    }
}

// ---------------------------------------------------------------------------
// k_e: raw E[b,d,h,v] = sum_c xl[b,c,h,v+2d]*xr[b,c,h,v] (0 when v+2d>=W).
// One block per (b,h), all 48 d; xl row staged transposed in LDS, xr column
// in 32 registers. No barriers after the single staging sync.
__global__ __launch_bounds__(448) void k_e(const float* __restrict__ xl,
                                           const float* __restrict__ xr,
                                           float* __restrict__ E) {
    __shared__ float sXL[W * LSTR];   // 59904 B
    int tid = threadIdx.x;
    int h = blockIdx.x;
    int b = blockIdx.y;
    int v = tid;
    bool act = v < W;
    const float* br = xr + (size_t)b * CHW + h * W;

    float xrv[C];
#pragma unroll
    for (int c = 0; c < C; ++c) xrv[c] = act ? br[c * HW + v] : 0.0f;

    stage_row(xl + (size_t)b * CHW + h * W, sXL, tid, 448);
    __syncthreads();
    if (!act) return;

    float* pe = E + (((size_t)b * D) * H + h) * W + v;
    for (int d = 0; d < D; ++d) {
        int s = 2 * d;
        float e = 0.0f;
        if (v + s < W) e = dot32(xrv, sXL + (v + s) * LSTR);
        pe[(size_t)d * HW] = e;
    }
}

// ---------------------------------------------------------------------------
// k_lr2: sLR = 3x3 window sum of E (h-1..h+1, vc-1..vc+1) times inverse
// norms. One block per (b,h), all 48 d; E rows are hot in L1/L2.
__global__ __launch_bounds__(448) void k_lr2(const float* __restrict__ E,
                                             const float* __restrict__ inl,
                                             const float* __restrict__ inr,
                                             float* __restrict__ out) {
    int tid = threadIdx.x;
    int h = blockIdx.x;
    int b = blockIdx.y;
    int w = tid;
    if (w >= W) return;
    int bhw = b * HW + h * W;

    float* o = out + ((size_t)b * 3 + 2) * D * HW + h * W + w;
    for (int d = 0; d < D; ++d) {
        float r = 0.0f;
        if (w >= d && w + d < W) {
            int vc = w - d;
            const float* base = E + ((size_t)b * D + d) * HW;
            float e = 0.0f;
#pragma unroll
            for (int dh = -1; dh <= 1; ++dh) {
                int hh = h + dh;
                if (hh < 0 || hh >= H) continue;
                const float* row = base + hh * W;
                float s = row[vc];
                if (vc - 1 >= 0) s += row[vc - 1];
                if (vc + 1 < W) s += row[vc + 1];
                e += s;
            }
            r = clip10(e * inl[bhw + w + d] * inr[bhw + vc] * ISCALE);
        }
        o[(size_t)d * HW] = r;
    }
}

// ---------------------------------------------------------------------------
extern "C" void kernel_launch(void* const* d_in, const int* in_sizes, int n_in,
                              void* d_out, int out_size, void* d_ws, size_t ws_size,
                              hipStream_t stream) {
    const float* xl = (const float*)d_in[0];
    const float* xm = (const float*)d_in[1];
    const float* xr = (const float*)d_in[2];
    float* out = (float*)d_out;

    float* ws = (float*)d_ws;
    float* boxl = ws;                              // B*C*H*W
    float* boxr = boxl + (size_t)B * CHW;          // B*C*H*W
    float* inl  = boxr + (size_t)B * CHW;          // B*HW
    float* inr  = inl + B * HW;                    // B*HW
    float* inm  = inr + B * HW;                    // B*HW
    float* sql  = inm + B * HW;                    // B*HW
    float* sqr  = sql + B * HW;                    // B*HW
    float* E    = sqr + B * HW;                    // B*D*H*W

    k_sq<<<dim3((B * HW + 255) / 256), dim3(256), 0, stream>>>(xl, xr, xm, sql, sqr, inm);
    k_norm<<<dim3((B * HW + 255) / 256), dim3(256), 0, stream>>>(sql, sqr, inl, inr);
    k_box<<<dim3((B * CHW + 255) / 256), dim3(256), 0, stream>>>(xl, xr, boxl, boxr);
    k_e<<<dim3(H, B), dim3(448), 0, stream>>>(xl, xr, E);
    k_lr<<<dim3(H, B), dim3(448), 0, stream>>>(xm, boxl, boxr, inl, inr, inm, out);
    k_lr2<<<dim3(H, B), dim3(448), 0, stream>>>(E, inl, inr, out);
}

// Round 3
// 218.609 us; speedup vs baseline: 1.8315x; 1.1878x over previous
//
#include <hip/hip_runtime.h>
#include <math.h>

#define B 2
#define C 32
#define H 128
#define W 416
#define D 48
#define HW (H*W)
#define CHW (C*HW)
#define EPSN 1e-3f
#define ISCALE 0.05892556509887896f   // 1/sqrt(C*9)
#define LSTR 36                        // LDS column stride (floats): 16B-aligned, bank-uniform

__device__ __forceinline__ float clip10(float x) {
    return fminf(fmaxf(x, -10.0f), 10.0f);
}

// ---------------------------------------------------------------------------
// k_sq: per-pixel sum over channels of squares for xl/xr; inverse norm for xm.
__global__ __launch_bounds__(256) void k_sq(const float* __restrict__ xl,
                                            const float* __restrict__ xr,
                                            const float* __restrict__ xm,
                                            float* __restrict__ sql,
                                            float* __restrict__ sqr,
                                            float* __restrict__ inm) {
    int idx = blockIdx.x * 256 + threadIdx.x;   // [0, B*HW)
    if (idx >= B * HW) return;
    int b = idx / HW, hw = idx - b * HW;
    const float* pl = xl + (size_t)b * CHW + hw;
    const float* pr = xr + (size_t)b * CHW + hw;
    const float* pm = xm + (size_t)b * CHW + hw;
    float al = 0.f, ar = 0.f, am = 0.f;
#pragma unroll
    for (int c = 0; c < C; ++c) {
        float vl = pl[c * HW], vr = pr[c * HW], vm = pm[c * HW];
        al += vl * vl; ar += vr * vr; am += vm * vm;
    }
    sql[idx] = al;
    sqr[idx] = ar;
    inm[idx] = 1.0f / fmaxf(sqrtf(am), EPSN);
}

// ---------------------------------------------------------------------------
// k_norm: 3x3 zero-padded box of sql/sqr -> inverse patch norms inl/inr.
__global__ __launch_bounds__(256) void k_norm(const float* __restrict__ sql,
                                              const float* __restrict__ sqr,
                                              float* __restrict__ inl,
                                              float* __restrict__ inr) {
    int idx = blockIdx.x * 256 + threadIdx.x;
    if (idx >= B * HW) return;
    int b = idx / HW, hw = idx - b * HW;
    int h = hw / W, w = hw - h * W;
    float sl = 0.f, sr = 0.f;
#pragma unroll
    for (int di = -1; di <= 1; ++di) {
        int hh = h + di;
        if (hh < 0 || hh >= H) continue;
#pragma unroll
        for (int dj = -1; dj <= 1; ++dj) {
            int ww = w + dj;
            if (ww < 0 || ww >= W) continue;
            int p = b * HW + hh * W + ww;
            sl += sql[p];
            sr += sqr[p];
        }
    }
    inl[idx] = 1.0f / fmaxf(sqrtf(sl), EPSN);
    inr[idx] = 1.0f / fmaxf(sqrtf(sr), EPSN);
}

// ---------------------------------------------------------------------------
// k_box: per-channel 3x3 zero-padded box sums of xl and xr.
__global__ __launch_bounds__(256) void k_box(const float* __restrict__ xl,
                                             const float* __restrict__ xr,
                                             float* __restrict__ boxl,
                                             float* __restrict__ boxr) {
    int idx = blockIdx.x * 256 + threadIdx.x;   // [0, B*C*H*W)
    int w = idx % W;
    int h = (idx / W) % H;
    int rest = idx / HW;                        // b*C + c
    size_t base = (size_t)rest * HW;
    float al = 0.f, ar = 0.f;
#pragma unroll
    for (int di = -1; di <= 1; ++di) {
        int hh = h + di;
        if (hh < 0 || hh >= H) continue;
#pragma unroll
        for (int dj = -1; dj <= 1; ++dj) {
            int ww = w + dj;
            if (ww < 0 || ww >= W) continue;
            al += xl[base + hh * W + ww];
            ar += xr[base + hh * W + ww];
        }
    }
    boxl[idx] = al;
    boxr[idx] = ar;
}

// ---------------------------------------------------------------------------
// helper: stage one [C][W] global row into LDS transposed [w][c] with stride LSTR
__device__ __forceinline__ void stage_row(const float* __restrict__ gsrc,
                                          float* __restrict__ lds, int tid, int nthreads) {
    for (int j = tid; j < (W / 4) * C; j += nthreads) {
        int c = j / (W / 4);
        int w4 = (j - c * (W / 4)) * 4;
        float4 v = *(const float4*)(gsrc + (size_t)c * HW + w4);
        lds[(w4 + 0) * LSTR + c] = v.x;
        lds[(w4 + 1) * LSTR + c] = v.y;
        lds[(w4 + 2) * LSTR + c] = v.z;
        lds[(w4 + 3) * LSTR + c] = v.w;
    }
}

__device__ __forceinline__ float dot32(const float* __restrict__ fl,
                                       const float* __restrict__ col) {
    const float4* c4 = (const float4*)col;   // 16B-aligned (LSTR*4 = 144)
    float a = 0.0f;
#pragma unroll
    for (int q = 0; q < 8; ++q) {
        float4 v = c4[q];
        a += fl[4 * q + 0] * v.x + fl[4 * q + 1] * v.y
           + fl[4 * q + 2] * v.z + fl[4 * q + 3] * v.w;
    }
    return a;
}

// ---------------------------------------------------------------------------
// k_lr: sL and sR for all 48 d. One block per (b,h). Two phases sharing one
// 60KB LDS buffer: stage boxl -> compute sL; stage boxr -> compute sR.
__global__ __launch_bounds__(448) void k_lr(const float* __restrict__ xm,
                                            const float* __restrict__ boxl,
                                            const float* __restrict__ boxr,
                                            const float* __restrict__ inl,
                                            const float* __restrict__ inr,
                                            const float* __restrict__ inm,
                                            float* __restrict__ out) {
    __shared__ float sB[W * LSTR];    // 59904 B
    __shared__ float sIn[W];
    int tid = threadIdx.x;
    int h = blockIdx.x;
    int b = blockIdx.y;
    int w = tid;
    bool act = w < W;
    int bhw = b * HW + h * W;
    const float* pm = xm + (size_t)b * CHW + h * W;

    float fl[C];
    float im = act ? inm[bhw + w] : 0.0f;
#pragma unroll
    for (int c = 0; c < C; ++c) fl[c] = act ? pm[c * HW + w] * im : 0.0f;

    // ---- phase L ----
    stage_row(boxl + (size_t)b * CHW + h * W, sB, tid, 448);
    for (int j = tid; j < W; j += 448) sIn[j] = inl[bhw + j];
    __syncthreads();
    if (act) {
        float* o = out + ((size_t)b * 3 + 0) * D * HW + h * W + w;
        for (int d = 0; d < D; ++d) {
            float oL = 0.0f;
            int v = w + d;
            if (v < W) {
                float a = dot32(fl, sB + v * LSTR);
                oL = clip10(a * sIn[v] * ISCALE);
            }
            o[(size_t)d * HW] = oL;
        }
    }
    __syncthreads();

    // ---- phase R ----
    stage_row(boxr + (size_t)b * CHW + h * W, sB, tid, 448);
    for (int j = tid; j < W; j += 448) sIn[j] = inr[bhw + j];
    __syncthreads();
    if (act) {
        float* o = out + ((size_t)b * 3 + 1) * D * HW + h * W + w;
        for (int d = 0; d < D; ++d) {
            float oR = 0.0f;
            int v = w - d;
            if (v >= 0) {
                float a = dot32(fl, sB + v * LSTR);
                oR = clip10(a * sIn[v] * ISCALE);
            }
            o[(size_t)d * HW] = oR;
        }
    }
}

// ---------------------------------------------------------------------------
// k_e: EH[b,d,h,v] = sum_{j=-1..1} E[b,d,h,v+j],
// E[v] = sum_c xl[b,c,h,v+2d]*xr[b,c,h,v] (0 outside [0,W) or v+2d>=W).
// Wave-halo layout: each 64-lane wave computes e at v = wave*62 + lane - 1
// and emits 62 horizontal 3-sums via shuffles — no barriers, no recompute.
__global__ __launch_bounds__(448) void k_e(const float* __restrict__ xl,
                                           const float* __restrict__ xr,
                                           float* __restrict__ EH) {
    __shared__ float sXL[W * LSTR];   // 59904 B
    int tid = threadIdx.x;
    int h = blockIdx.x;
    int b = blockIdx.y;
    int lane = tid & 63;
    int wv = tid >> 6;                // 0..6
    int v = wv * 62 + lane - 1;       // -1 .. 433
    bool vin = (v >= 0) && (v < W);
    const float* br = xr + (size_t)b * CHW + h * W;

    float xrv[C];
#pragma unroll
    for (int c = 0; c < C; ++c) xrv[c] = vin ? br[c * HW + v] : 0.0f;

    stage_row(xl + (size_t)b * CHW + h * W, sXL, tid, 448);
    __syncthreads();

    bool wr = (lane >= 1) && (lane <= 62) && (v < W);   // v>=0 implied
    float* pe = EH + (((size_t)b * D) * H + h) * W + v;
    for (int d = 0; d < D; ++d) {
        int s = 2 * d;
        float e = 0.0f;
        if (vin && v + s < W) e = dot32(xrv, sXL + (v + s) * LSTR);
        float em = __shfl_up(e, 1);
        float ep = __shfl_down(e, 1);
        float eh = em + e + ep;
        if (wr) pe[(size_t)d * HW] = eh;
    }
}

// ---------------------------------------------------------------------------
// k_lr2: sLR = vertical 3-tap of EH at column vc=w-d, times inverse norms.
// Block handles 12 d for one (b,h); fully unrolled for load ILP.
#define DCH 12
__global__ __launch_bounds__(448) void k_lr2(const float* __restrict__ EH,
                                             const float* __restrict__ inl,
                                             const float* __restrict__ inr,
                                             float* __restrict__ out) {
    int w = threadIdx.x;
    int dc = blockIdx.x;              // 0..3
    int h = blockIdx.y;
    int b = blockIdx.z;
    if (w >= W) return;
    int bhw = b * HW + h * W;
    bool hm = (h > 0), hp = (h < H - 1);

    float* o = out + ((size_t)b * 3 + 2) * D * HW + h * W + w;
#pragma unroll
    for (int i = 0; i < DCH; ++i) {
        int d = dc * DCH + i;
        float r = 0.0f;
        if (w >= d && w + d < W) {
            int vc = w - d;
            const float* base = EH + ((size_t)b * D + d) * HW + vc;
            float e = base[h * W];
            if (hm) e += base[(h - 1) * W];
            if (hp) e += base[(h + 1) * W];
            float nl = inl[bhw + w + d];
            float nr = inr[bhw + vc];
            r = clip10(e * nl * nr * ISCALE);
        }
        o[(size_t)d * HW] = r;
    }
}

// ---------------------------------------------------------------------------
extern "C" void kernel_launch(void* const* d_in, const int* in_sizes, int n_in,
                              void* d_out, int out_size, void* d_ws, size_t ws_size,
                              hipStream_t stream) {
    const float* xl = (const float*)d_in[0];
    const float* xm = (const float*)d_in[1];
    const float* xr = (const float*)d_in[2];
    float* out = (float*)d_out;

    float* ws = (float*)d_ws;
    float* boxl = ws;                              // B*C*H*W
    float* boxr = boxl + (size_t)B * CHW;          // B*C*H*W
    float* inl  = boxr + (size_t)B * CHW;          // B*HW
    float* inr  = inl + B * HW;                    // B*HW
    float* inm  = inr + B * HW;                    // B*HW
    float* sql  = inm + B * HW;                    // B*HW
    float* sqr  = sql + B * HW;                    // B*HW
    float* EH   = sqr + B * HW;                    // B*D*H*W

    k_sq<<<dim3((B * HW + 255) / 256), dim3(256), 0, stream>>>(xl, xr, xm, sql, sqr, inm);
    k_norm<<<dim3((B * HW + 255) / 256), dim3(256), 0, stream>>>(sql, sqr, inl, inr);
    k_box<<<dim3((B * CHW + 255) / 256), dim3(256), 0, stream>>>(xl, xr, boxl, boxr);
    k_e<<<dim3(H, B), dim3(448), 0, stream>>>(xl, xr, EH);
    k_lr<<<dim3(H, B), dim3(448), 0, stream>>>(xm, boxl, boxr, inl, inr, inm, out);
    k_lr2<<<dim3(4, H, B), dim3(448), 0, stream>>>(EH, inl, inr, out);
}

// Round 4
// 200.845 us; speedup vs baseline: 1.9935x; 1.0884x over previous
//
#include <hip/hip_runtime.h>
#include <math.h>

#define B 2
#define C 32
#define H 128
#define W 416
#define D 48
#define HW (H*W)
#define CHW (C*HW)
#define EPSN 1e-3f
#define ISCALE 0.05892556509887896f   // 1/sqrt(C*9)
#define LSTR 36                        // LDS column stride (floats): 16B-aligned, bank-uniform

__device__ __forceinline__ float clip10(float x) {
    return fminf(fmaxf(x, -10.0f), 10.0f);
}

// ---------------------------------------------------------------------------
// k_sq: per-pixel sum over channels of squares for xl/xr; inverse norm for xm.
__global__ __launch_bounds__(256) void k_sq(const float* __restrict__ xl,
                                            const float* __restrict__ xr,
                                            const float* __restrict__ xm,
                                            float* __restrict__ sql,
                                            float* __restrict__ sqr,
                                            float* __restrict__ inm) {
    int idx = blockIdx.x * 256 + threadIdx.x;   // [0, B*HW)
    if (idx >= B * HW) return;
    int b = idx / HW, hw = idx - b * HW;
    const float* pl = xl + (size_t)b * CHW + hw;
    const float* pr = xr + (size_t)b * CHW + hw;
    const float* pm = xm + (size_t)b * CHW + hw;
    float al = 0.f, ar = 0.f, am = 0.f;
#pragma unroll
    for (int c = 0; c < C; ++c) {
        float vl = pl[c * HW], vr = pr[c * HW], vm = pm[c * HW];
        al += vl * vl; ar += vr * vr; am += vm * vm;
    }
    sql[idx] = al;
    sqr[idx] = ar;
    inm[idx] = 1.0f / fmaxf(sqrtf(am), EPSN);
}

// ---------------------------------------------------------------------------
// k_norm: 3x3 zero-padded box of sql/sqr -> inverse patch norms inl/inr.
__global__ __launch_bounds__(256) void k_norm(const float* __restrict__ sql,
                                              const float* __restrict__ sqr,
                                              float* __restrict__ inl,
                                              float* __restrict__ inr) {
    int idx = blockIdx.x * 256 + threadIdx.x;
    if (idx >= B * HW) return;
    int b = idx / HW, hw = idx - b * HW;
    int h = hw / W, w = hw - h * W;
    float sl = 0.f, sr = 0.f;
#pragma unroll
    for (int di = -1; di <= 1; ++di) {
        int hh = h + di;
        if (hh < 0 || hh >= H) continue;
#pragma unroll
        for (int dj = -1; dj <= 1; ++dj) {
            int ww = w + dj;
            if (ww < 0 || ww >= W) continue;
            int p = b * HW + hh * W + ww;
            sl += sql[p];
            sr += sqr[p];
        }
    }
    inl[idx] = 1.0f / fmaxf(sqrtf(sl), EPSN);
    inr[idx] = 1.0f / fmaxf(sqrtf(sr), EPSN);
}

// ---------------------------------------------------------------------------
// k_box: per-channel 3x3 zero-padded box sums, vectorized: 4 outputs/thread,
// horizontal 3-sum in registers (3 float4 + 6 scalar loads per 4 outputs).
__global__ __launch_bounds__(256) void k_box(const float* __restrict__ xl,
                                             const float* __restrict__ xr,
                                             float* __restrict__ boxl,
                                             float* __restrict__ boxr) {
    int idx = blockIdx.x * 256 + threadIdx.x;   // [0, B*C*H*W/4)
    int w4 = (idx % (W / 4)) * 4;
    int h = (idx / (W / 4)) % H;
    int rest = idx / (H * (W / 4));             // b*C + c
    size_t base = (size_t)rest * HW;
    float4 al = {0.f, 0.f, 0.f, 0.f}, ar = {0.f, 0.f, 0.f, 0.f};
#pragma unroll
    for (int dh = -1; dh <= 1; ++dh) {
        int hh = h + dh;
        if (hh < 0 || hh >= H) continue;
        const float* rl = xl + base + hh * W;
        const float* rr = xr + base + hh * W;
        float4 m = *(const float4*)(rl + w4);
        float lm = (w4 > 0) ? rl[w4 - 1] : 0.f;
        float rm = (w4 + 4 < W) ? rl[w4 + 4] : 0.f;
        al.x += lm + m.x + m.y;  al.y += m.x + m.y + m.z;
        al.z += m.y + m.z + m.w; al.w += m.z + m.w + rm;
        float4 n = *(const float4*)(rr + w4);
        float ln = (w4 > 0) ? rr[w4 - 1] : 0.f;
        float rn = (w4 + 4 < W) ? rr[w4 + 4] : 0.f;
        ar.x += ln + n.x + n.y;  ar.y += n.x + n.y + n.z;
        ar.z += n.y + n.z + n.w; ar.w += n.z + n.w + rn;
    }
    *(float4*)(boxl + base + h * W + w4) = al;
    *(float4*)(boxr + base + h * W + w4) = ar;
}

// ---------------------------------------------------------------------------
// helper: stage one [C][W] global row into LDS transposed [w][c] with stride LSTR
__device__ __forceinline__ void stage_row(const float* __restrict__ gsrc,
                                          float* __restrict__ lds, int tid, int nthreads) {
    for (int j = tid; j < (W / 4) * C; j += nthreads) {
        int c = j / (W / 4);
        int w4 = (j - c * (W / 4)) * 4;
        float4 v = *(const float4*)(gsrc + (size_t)c * HW + w4);
        lds[(w4 + 0) * LSTR + c] = v.x;
        lds[(w4 + 1) * LSTR + c] = v.y;
        lds[(w4 + 2) * LSTR + c] = v.z;
        lds[(w4 + 3) * LSTR + c] = v.w;
    }
}

__device__ __forceinline__ float dot32(const float* __restrict__ fl,
                                       const float* __restrict__ col) {
    const float4* c4 = (const float4*)col;   // 16B-aligned (LSTR*4 = 144)
    float a = 0.0f;
#pragma unroll
    for (int q = 0; q < 8; ++q) {
        float4 v = c4[q];
        a += fl[4 * q + 0] * v.x + fl[4 * q + 1] * v.y
           + fl[4 * q + 2] * v.z + fl[4 * q + 3] * v.w;
    }
    return a;
}

// ---------------------------------------------------------------------------
// k_lr: sL and sR. One block per (b,h,dc); dc splits the 48 disparities in
// two so 2 blocks/CU are resident (LDS 60KB -> exactly 2 fit). Two phases
// share one buffer: stage boxl -> sL, stage boxr -> sR.
#define DSPL (D / 2)
__global__ __launch_bounds__(448) void k_lr(const float* __restrict__ xm,
                                            const float* __restrict__ boxl,
                                            const float* __restrict__ boxr,
                                            const float* __restrict__ inl,
                                            const float* __restrict__ inr,
                                            const float* __restrict__ inm,
                                            float* __restrict__ out) {
    __shared__ float sB[W * LSTR];    // 59904 B
    __shared__ float sIn[W];
    int tid = threadIdx.x;
    int h = blockIdx.x;
    int b = blockIdx.y;
    int d0 = blockIdx.z * DSPL;
    int w = tid;
    bool act = w < W;
    int bhw = b * HW + h * W;
    const float* pm = xm + (size_t)b * CHW + h * W;

    float fl[C];
    float im = act ? inm[bhw + w] : 0.0f;
#pragma unroll
    for (int c = 0; c < C; ++c) fl[c] = act ? pm[c * HW + w] * im : 0.0f;

    // ---- phase L ----
    stage_row(boxl + (size_t)b * CHW + h * W, sB, tid, 448);
    for (int j = tid; j < W; j += 448) sIn[j] = inl[bhw + j];
    __syncthreads();
    if (act) {
        float* o = out + ((size_t)b * 3 + 0) * D * HW + h * W + w;
        for (int d = d0; d < d0 + DSPL; ++d) {
            float oL = 0.0f;
            int v = w + d;
            if (v < W) {
                float a = dot32(fl, sB + v * LSTR);
                oL = clip10(a * sIn[v] * ISCALE);
            }
            o[(size_t)d * HW] = oL;
        }
    }
    __syncthreads();

    // ---- phase R ----
    stage_row(boxr + (size_t)b * CHW + h * W, sB, tid, 448);
    for (int j = tid; j < W; j += 448) sIn[j] = inr[bhw + j];
    __syncthreads();
    if (act) {
        float* o = out + ((size_t)b * 3 + 1) * D * HW + h * W + w;
        for (int d = d0; d < d0 + DSPL; ++d) {
            float oR = 0.0f;
            int v = w - d;
            if (v >= 0) {
                float a = dot32(fl, sB + v * LSTR);
                oR = clip10(a * sIn[v] * ISCALE);
            }
            o[(size_t)d * HW] = oR;
        }
    }
}

// ---------------------------------------------------------------------------
// k_e: EH[b,d,h,v] = horizontal 3-tap of E, E[v] = sum_c xl[.,v+2d]*xr[.,v].
// Wave-halo: each wave computes e at v = wave*62 + lane - 1, emits 62 sums
// via shuffles. dc splits d in two -> 2 blocks/CU resident.
__global__ __launch_bounds__(448) void k_e(const float* __restrict__ xl,
                                           const float* __restrict__ xr,
                                           float* __restrict__ EH) {
    __shared__ float sXL[W * LSTR];   // 59904 B
    int tid = threadIdx.x;
    int h = blockIdx.x;
    int b = blockIdx.y;
    int d0 = blockIdx.z * DSPL;
    int lane = tid & 63;
    int wv = tid >> 6;                // 0..6
    int v = wv * 62 + lane - 1;       // -1 .. 433
    bool vin = (v >= 0) && (v < W);
    const float* br = xr + (size_t)b * CHW + h * W;

    float xrv[C];
#pragma unroll
    for (int c = 0; c < C; ++c) xrv[c] = vin ? br[c * HW + v] : 0.0f;

    stage_row(xl + (size_t)b * CHW + h * W, sXL, tid, 448);
    __syncthreads();

    bool wr = (lane >= 1) && (lane <= 62) && (v < W);   // v>=0 implied
    float* pe = EH + (((size_t)b * D) * H + h) * W + v;
    for (int d = d0; d < d0 + DSPL; ++d) {
        int s = 2 * d;
        float e = 0.0f;
        if (vin && v + s < W) e = dot32(xrv, sXL + (v + s) * LSTR);
        float em = __shfl_up(e, 1);
        float ep = __shfl_down(e, 1);
        float eh = em + e + ep;
        if (wr) pe[(size_t)d * HW] = eh;
    }
}

// ---------------------------------------------------------------------------
// k_lr2: sLR = vertical 3-tap of EH at column vc=w-d, times inverse norms.
#define DCH 12
__global__ __launch_bounds__(448) void k_lr2(const float* __restrict__ EH,
                                             const float* __restrict__ inl,
                                             const float* __restrict__ inr,
                                             float* __restrict__ out) {
    int w = threadIdx.x;
    int dc = blockIdx.x;              // 0..3
    int h = blockIdx.y;
    int b = blockIdx.z;
    if (w >= W) return;
    int bhw = b * HW + h * W;
    bool hm = (h > 0), hp = (h < H - 1);

    float* o = out + ((size_t)b * 3 + 2) * D * HW + h * W + w;
#pragma unroll
    for (int i = 0; i < DCH; ++i) {
        int d = dc * DCH + i;
        float r = 0.0f;
        if (w >= d && w + d < W) {
            int vc = w - d;
            const float* base = EH + ((size_t)b * D + d) * HW + vc;
            float e = base[h * W];
            if (hm) e += base[(h - 1) * W];
            if (hp) e += base[(h + 1) * W];
            float nl = inl[bhw + w + d];
            float nr = inr[bhw + vc];
            r = clip10(e * nl * nr * ISCALE);
        }
        o[(size_t)d * HW] = r;
    }
}

// ---------------------------------------------------------------------------
extern "C" void kernel_launch(void* const* d_in, const int* in_sizes, int n_in,
                              void* d_out, int out_size, void* d_ws, size_t ws_size,
                              hipStream_t stream) {
    const float* xl = (const float*)d_in[0];
    const float* xm = (const float*)d_in[1];
    const float* xr = (const float*)d_in[2];
    float* out = (float*)d_out;

    float* ws = (float*)d_ws;
    float* boxl = ws;                              // B*C*H*W
    float* boxr = boxl + (size_t)B * CHW;          // B*C*H*W
    float* inl  = boxr + (size_t)B * CHW;          // B*HW
    float* inr  = inl + B * HW;                    // B*HW
    float* inm  = inr + B * HW;                    // B*HW
    float* sql  = inm + B * HW;                    // B*HW
    float* sqr  = sql + B * HW;                    // B*HW
    float* EH   = sqr + B * HW;                    // B*D*H*W

    k_sq<<<dim3((B * HW + 255) / 256), dim3(256), 0, stream>>>(xl, xr, xm, sql, sqr, inm);
    k_norm<<<dim3((B * HW + 255) / 256), dim3(256), 0, stream>>>(sql, sqr, inl, inr);
    k_box<<<dim3((B * CHW / 4 + 255) / 256), dim3(256), 0, stream>>>(xl, xr, boxl, boxr);
    k_e<<<dim3(H, B, 2), dim3(448), 0, stream>>>(xl, xr, EH);
    k_lr<<<dim3(H, B, 2), dim3(448), 0, stream>>>(xm, boxl, boxr, inl, inr, inm, out);
    k_lr2<<<dim3(4, H, B), dim3(448), 0, stream>>>(EH, inl, inr, out);
}

// Round 5
// 193.148 us; speedup vs baseline: 2.0729x; 1.0399x over previous
//
#include <hip/hip_runtime.h>
#include <math.h>

#define B 2
#define C 32
#define H 128
#define W 416
#define D 48
#define HW (H*W)
#define CHW (C*HW)
#define EPSN 1e-3f
#define ISCALE 0.05892556509887896f   // 1/sqrt(C*9)
#define LSTR 36                        // LDS column stride (floats): 16B-aligned
#define DSPL (D / 2)                   // disparities per block (d-split)

__device__ __forceinline__ float clip10(float x) {
    return fminf(fmaxf(x, -10.0f), 10.0f);
}

// ---------------------------------------------------------------------------
// k_sq: per-pixel sum over channels of squares for xl/xr; inverse norm for xm.
__global__ __launch_bounds__(256) void k_sq(const float* __restrict__ xl,
                                            const float* __restrict__ xr,
                                            const float* __restrict__ xm,
                                            float* __restrict__ sql,
                                            float* __restrict__ sqr,
                                            float* __restrict__ inm) {
    int idx = blockIdx.x * 256 + threadIdx.x;   // [0, B*HW)
    if (idx >= B * HW) return;
    int b = idx / HW, hw = idx - b * HW;
    const float* pl = xl + (size_t)b * CHW + hw;
    const float* pr = xr + (size_t)b * CHW + hw;
    const float* pm = xm + (size_t)b * CHW + hw;
    float al = 0.f, ar = 0.f, am = 0.f;
#pragma unroll
    for (int c = 0; c < C; ++c) {
        float vl = pl[c * HW], vr = pr[c * HW], vm = pm[c * HW];
        al += vl * vl; ar += vr * vr; am += vm * vm;
    }
    sql[idx] = al;
    sqr[idx] = ar;
    inm[idx] = 1.0f / fmaxf(sqrtf(am), EPSN);
}

// ---------------------------------------------------------------------------
// k_norm: 3x3 zero-padded box of sql/sqr -> inverse patch norms inl/inr.
__global__ __launch_bounds__(256) void k_norm(const float* __restrict__ sql,
                                              const float* __restrict__ sqr,
                                              float* __restrict__ inl,
                                              float* __restrict__ inr) {
    int idx = blockIdx.x * 256 + threadIdx.x;
    if (idx >= B * HW) return;
    int b = idx / HW, hw = idx - b * HW;
    int h = hw / W, w = hw - h * W;
    float sl = 0.f, sr = 0.f;
#pragma unroll
    for (int di = -1; di <= 1; ++di) {
        int hh = h + di;
        if (hh < 0 || hh >= H) continue;
#pragma unroll
        for (int dj = -1; dj <= 1; ++dj) {
            int ww = w + dj;
            if (ww < 0 || ww >= W) continue;
            int p = b * HW + hh * W + ww;
            sl += sql[p];
            sr += sqr[p];
        }
    }
    inl[idx] = 1.0f / fmaxf(sqrtf(sl), EPSN);
    inr[idx] = 1.0f / fmaxf(sqrtf(sr), EPSN);
}

// ---------------------------------------------------------------------------
// k_box: per-channel 3x3 zero-padded box sums, vectorized: 4 outputs/thread.
__global__ __launch_bounds__(256) void k_box(const float* __restrict__ xl,
                                             const float* __restrict__ xr,
                                             float* __restrict__ boxl,
                                             float* __restrict__ boxr) {
    int idx = blockIdx.x * 256 + threadIdx.x;   // [0, B*C*H*W/4)
    int w4 = (idx % (W / 4)) * 4;
    int h = (idx / (W / 4)) % H;
    int rest = idx / (H * (W / 4));             // b*C + c
    size_t base = (size_t)rest * HW;
    float4 al = {0.f, 0.f, 0.f, 0.f}, ar = {0.f, 0.f, 0.f, 0.f};
#pragma unroll
    for (int dh = -1; dh <= 1; ++dh) {
        int hh = h + dh;
        if (hh < 0 || hh >= H) continue;
        const float* rl = xl + base + hh * W;
        const float* rr = xr + base + hh * W;
        float4 m = *(const float4*)(rl + w4);
        float lm = (w4 > 0) ? rl[w4 - 1] : 0.f;
        float rm = (w4 + 4 < W) ? rl[w4 + 4] : 0.f;
        al.x += lm + m.x + m.y;  al.y += m.x + m.y + m.z;
        al.z += m.y + m.z + m.w; al.w += m.z + m.w + rm;
        float4 n = *(const float4*)(rr + w4);
        float ln = (w4 > 0) ? rr[w4 - 1] : 0.f;
        float rn = (w4 + 4 < W) ? rr[w4 + 4] : 0.f;
        ar.x += ln + n.x + n.y;  ar.y += n.x + n.y + n.z;
        ar.z += n.y + n.z + n.w; ar.w += n.z + n.w + rn;
    }
    *(float4*)(boxl + base + h * W + w4) = al;
    *(float4*)(boxr + base + h * W + w4) = ar;
}

// ---------------------------------------------------------------------------
// stage_row_v2: stage [C][W] row into LDS transposed [w][c], stride LSTR.
// Lane mapping t = [g | cl(3b) | rw(3b)]: 8 w-quads x 8 channels per wave
// -> write banks (16*(rw&1) + 4k + cl)%32 = 16 banks, 4-way (vs 32-way for
// the naive map). Global side: 8 x 128B segments per wave.
__device__ __forceinline__ void stage_row_v2(const float* __restrict__ gsrc,
                                             float* __restrict__ lds,
                                             int tid, int nthreads) {
    for (int t = tid; t < (W / 4) * C; t += nthreads) {
        int rw = t & 7;
        int cl = (t >> 3) & 7;
        int g  = t >> 6;              // 0..51
        int wg = g % 13;
        int ch = g / 13;              // 0..3
        int c  = ch * 8 + cl;
        int w4 = (wg * 8 + rw) * 4;
        float4 v = *(const float4*)(gsrc + (size_t)c * HW + w4);
        lds[(w4 + 0) * LSTR + c] = v.x;
        lds[(w4 + 1) * LSTR + c] = v.y;
        lds[(w4 + 2) * LSTR + c] = v.z;
        lds[(w4 + 3) * LSTR + c] = v.w;
    }
}

__device__ __forceinline__ float dot32(const float* __restrict__ fl,
                                       const float* __restrict__ col) {
    const float4* c4 = (const float4*)col;   // 16B-aligned (LSTR*4 = 144)
    float a = 0.0f;
#pragma unroll
    for (int q = 0; q < 8; ++q) {
        float4 v = c4[q];
        a += fl[4 * q + 0] * v.x + fl[4 * q + 1] * v.y
           + fl[4 * q + 2] * v.z + fl[4 * q + 3] * v.w;
    }
    return a;
}

// one column read -> two dots (w and w+1 fragments)
__device__ __forceinline__ void dot32x2(const float* __restrict__ fl0,
                                        const float* __restrict__ fl1,
                                        const float* __restrict__ col,
                                        float& a0, float& a1) {
    const float4* c4 = (const float4*)col;
    float s0 = 0.f, s1 = 0.f;
#pragma unroll
    for (int q = 0; q < 8; ++q) {
        float4 v = c4[q];
        s0 += fl0[4 * q + 0] * v.x + fl0[4 * q + 1] * v.y
            + fl0[4 * q + 2] * v.z + fl0[4 * q + 3] * v.w;
        s1 += fl1[4 * q + 0] * v.x + fl1[4 * q + 1] * v.y
            + fl1[4 * q + 2] * v.z + fl1[4 * q + 3] * v.w;
    }
    a0 = s0; a1 = s1;
}

// ---------------------------------------------------------------------------
// k_lr: sL and sR. One block per (b,h,dc). 2-w register tiling: thread owns
// (w,w+1), one LDS column read feeds two dots; paired float2 stores.
__global__ __launch_bounds__(256) void k_lr(const float* __restrict__ xm,
                                            const float* __restrict__ boxl,
                                            const float* __restrict__ boxr,
                                            const float* __restrict__ inl,
                                            const float* __restrict__ inr,
                                            const float* __restrict__ inm,
                                            float* __restrict__ out) {
    __shared__ float sB[W * LSTR];    // 59904 B
    __shared__ float sIn[W];
    int tid = threadIdx.x;
    int h = blockIdx.x;
    int b = blockIdx.y;
    int d0 = blockIdx.z * DSPL;
    bool act = tid < (W / 2);         // 208 pairs
    int w = 2 * tid;
    int bhw = b * HW + h * W;
    const float* pm = xm + (size_t)b * CHW + h * W;

    float fl0[C], fl1[C];
    if (act) {
        float2 im = *(const float2*)(inm + bhw + w);
#pragma unroll
        for (int c = 0; c < C; ++c) {
            float2 mv = *(const float2*)(pm + c * HW + w);
            fl0[c] = mv.x * im.x;
            fl1[c] = mv.y * im.y;
        }
    } else {
#pragma unroll
        for (int c = 0; c < C; ++c) { fl0[c] = 0.f; fl1[c] = 0.f; }
    }

    // ---- phase L: cols v = w+d0+j, j=0..DSPL; store d=d0+j-1 at iter j ----
    stage_row_v2(boxl + (size_t)b * CHW + h * W, sB, tid, 256);
    for (int j = tid; j < W; j += 256) sIn[j] = inl[bhw + j];
    __syncthreads();
    if (act) {
        float* o = out + ((size_t)b * 3 + 0) * D * HW + h * W;
        float a0p = 0.f;
#pragma unroll 4
        for (int j = 0; j <= DSPL; ++j) {
            int v = w + d0 + j;
            float a0 = 0.f, a1 = 0.f;
            if (v < W) {
                dot32x2(fl0, fl1, sB + v * LSTR, a0, a1);
                float s = sIn[v] * ISCALE;
                a0 = clip10(a0 * s);
                a1 = clip10(a1 * s);
            }
            if (j >= 1) {
                int d = d0 + j - 1;
                *(float2*)(o + (size_t)d * HW + w) = make_float2(a0p, a1);
            }
            a0p = a0;
        }
    }
    __syncthreads();

    // ---- phase R: cols v = w-d0-23+j, j=0..DSPL; store d=d0+24-j at iter j
    stage_row_v2(boxr + (size_t)b * CHW + h * W, sB, tid, 256);
    for (int j = tid; j < W; j += 256) sIn[j] = inr[bhw + j];
    __syncthreads();
    if (act) {
        float* o = out + ((size_t)b * 3 + 1) * D * HW + h * W;
        float a0p = 0.f;
#pragma unroll 4
        for (int j = 0; j <= DSPL; ++j) {
            int v = w - d0 - (DSPL - 1) + j;
            float a0 = 0.f, a1 = 0.f;
            if (v >= 0) {
                dot32x2(fl0, fl1, sB + v * LSTR, a0, a1);
                float s = sIn[v] * ISCALE;
                a0 = clip10(a0 * s);
                a1 = clip10(a1 * s);
            }
            if (j >= 1) {
                int d = d0 + DSPL - j;   // a0p: (w,d) from col v-1; a1: (w+1,d)
                *(float2*)(o + (size_t)d * HW + w) = make_float2(a0p, a1);
            }
            a0p = a0;
        }
    }
}

// ---------------------------------------------------------------------------
// k_e: EH[b,d,h,v] = horizontal 3-tap of E, E[v] = sum_c xl[.,v+2d]*xr[.,v].
// Wave-halo: each wave computes e at v = wave*62 + lane - 1, emits 62 sums
// via shuffles. dc splits d in two -> 2 blocks/CU resident.
__global__ __launch_bounds__(448) void k_e(const float* __restrict__ xl,
                                           const float* __restrict__ xr,
                                           float* __restrict__ EH) {
    __shared__ float sXL[W * LSTR];   // 59904 B
    int tid = threadIdx.x;
    int h = blockIdx.x;
    int b = blockIdx.y;
    int d0 = blockIdx.z * DSPL;
    int lane = tid & 63;
    int wv = tid >> 6;                // 0..6
    int v = wv * 62 + lane - 1;       // -1 .. 433
    bool vin = (v >= 0) && (v < W);
    const float* br = xr + (size_t)b * CHW + h * W;

    float xrv[C];
#pragma unroll
    for (int c = 0; c < C; ++c) xrv[c] = vin ? br[c * HW + v] : 0.0f;

    stage_row_v2(xl + (size_t)b * CHW + h * W, sXL, tid, 448);
    __syncthreads();

    bool wr = (lane >= 1) && (lane <= 62) && (v < W);   // v>=0 implied
    float* pe = EH + (((size_t)b * D) * H + h) * W + v;
    for (int d = d0; d < d0 + DSPL; ++d) {
        int s = 2 * d;
        float e = 0.0f;
        if (vin && v + s < W) e = dot32(xrv, sXL + (v + s) * LSTR);
        float em = __shfl_up(e, 1);
        float ep = __shfl_down(e, 1);
        float eh = em + e + ep;
        if (wr) pe[(size_t)d * HW] = eh;
    }
}

// ---------------------------------------------------------------------------
// k_lr2: sLR = vertical 3-tap of EH at column vc=w-d, times inverse norms.
#define DCH 12
__global__ __launch_bounds__(448) void k_lr2(const float* __restrict__ EH,
                                             const float* __restrict__ inl,
                                             const float* __restrict__ inr,
                                             float* __restrict__ out) {
    int w = threadIdx.x;
    int dc = blockIdx.x;              // 0..3
    int h = blockIdx.y;
    int b = blockIdx.z;
    if (w >= W) return;
    int bhw = b * HW + h * W;
    bool hm = (h > 0), hp = (h < H - 1);

    float* o = out + ((size_t)b * 3 + 2) * D * HW + h * W + w;
#pragma unroll
    for (int i = 0; i < DCH; ++i) {
        int d = dc * DCH + i;
        float r = 0.0f;
        if (w >= d && w + d < W) {
            int vc = w - d;
            const float* base = EH + ((size_t)b * D + d) * HW + vc;
            float e = base[h * W];
            if (hm) e += base[(h - 1) * W];
            if (hp) e += base[(h + 1) * W];
            float nl = inl[bhw + w + d];
            float nr = inr[bhw + vc];
            r = clip10(e * nl * nr * ISCALE);
        }
        o[(size_t)d * HW] = r;
    }
}

// ---------------------------------------------------------------------------
extern "C" void kernel_launch(void* const* d_in, const int* in_sizes, int n_in,
                              void* d_out, int out_size, void* d_ws, size_t ws_size,
                              hipStream_t stream) {
    const float* xl = (const float*)d_in[0];
    const float* xm = (const float*)d_in[1];
    const float* xr = (const float*)d_in[2];
    float* out = (float*)d_out;

    float* ws = (float*)d_ws;
    float* boxl = ws;                              // B*C*H*W
    float* boxr = boxl + (size_t)B * CHW;          // B*C*H*W
    float* inl  = boxr + (size_t)B * CHW;          // B*HW
    float* inr  = inl + B * HW;                    // B*HW
    float* inm  = inr + B * HW;                    // B*HW
    float* sql  = inm + B * HW;                    // B*HW
    float* sqr  = sql + B * HW;                    // B*HW
    float* EH   = sqr + B * HW;                    // B*D*H*W

    k_sq<<<dim3((B * HW + 255) / 256), dim3(256), 0, stream>>>(xl, xr, xm, sql, sqr, inm);
    k_norm<<<dim3((B * HW + 255) / 256), dim3(256), 0, stream>>>(sql, sqr, inl, inr);
    k_box<<<dim3((B * CHW / 4 + 255) / 256), dim3(256), 0, stream>>>(xl, xr, boxl, boxr);
    k_e<<<dim3(H, B, 2), dim3(448), 0, stream>>>(xl, xr, EH);
    k_lr<<<dim3(H, B, 2), dim3(256), 0, stream>>>(xm, boxl, boxr, inl, inr, inm, out);
    k_lr2<<<dim3(4, H, B), dim3(448), 0, stream>>>(EH, inl, inr, out);
}